// Round 1
// baseline (479.813 us; speedup 1.0000x reference)
//
#include <hip/hip_runtime.h>
#include <math.h>

// GLA forward, chunked. T=2048, B=8, IN=512, DV=512, NK=128, CHUNK=128, NCH=16.
// Layouts (all fp32, r = t_global*8 + b is the global row):
//   v_buf[r*512 + d], k_buf/q_buf/a_buf[r*128 + n]   (k_buf/q_buf become k~/q~ in-place)
//   A_buf[(c*8+b)*16384 + t*128 + s]  (masked s<=t)
//   G_buf[((c*8+b)*128 + n)*512 + d]  (local state contrib; scan overwrites with S_prev[c])
//   cpend[(c*8+b)*128 + n]

#define EPSV 1e-8f

enum { MODE_A = 0, MODE_Y = 1, MODE_G = 2, MODE_C = 3 };

// ---- LDS tile loaders: tile is 32 (K) x 128 (cols), row pitch 132 floats ----
// direct: lds[kk][col] = src[(k0+kk)*stride + col]
__device__ __forceinline__ void load_direct(float* lds, const float* __restrict__ src,
                                            long stride, int k0, int tid) {
#pragma unroll
  for (int it = 0; it < 4; ++it) {
    int f = tid + 256 * it;            // 0..1023
    int kk = f >> 5;                   // 0..31
    int c4 = f & 31;                   // 0..31 (float4 col)
    float4 val = *(const float4*)(src + (long)(k0 + kk) * stride + (c4 << 2));
    *(float4*)(lds + kk * 132 + (c4 << 2)) = val;
  }
}

// transpose: lds[kk][m] = src[m*stride + k0+kk]
__device__ __forceinline__ void load_trans(float* lds, const float* __restrict__ src,
                                           long stride, int k0, int tid) {
#pragma unroll
  for (int it = 0; it < 4; ++it) {
    int f = tid + 256 * it;            // 0..1023
    int m = f >> 3;                    // 0..127
    int kq = f & 7;                    // 0..7 (float4 along k)
    float4 val = *(const float4*)(src + (long)m * stride + k0 + (kq << 2));
    lds[(kq * 4 + 0) * 132 + m] = val.x;
    lds[(kq * 4 + 1) * 132 + m] = val.y;
    lds[(kq * 4 + 2) * 132 + m] = val.z;
    lds[(kq * 4 + 3) * 132 + m] = val.w;
  }
}

__device__ __forceinline__ void mm_inner(const float* lp, const float* lv,
                                         float acc[8][8], int tx, int ty) {
#pragma unroll 8
  for (int kk = 0; kk < 32; ++kk) {
    const float* lpr = lp + kk * 132;
    const float* lvr = lv + kk * 132;
    float a[8], bb[8];
    *(float4*)(a)      = *(const float4*)(lpr + tx * 8);
    *(float4*)(a + 4)  = *(const float4*)(lpr + tx * 8 + 4);
    *(float4*)(bb)     = *(const float4*)(lvr + ty * 8);
    *(float4*)(bb + 4) = *(const float4*)(lvr + ty * 8 + 4);
#pragma unroll
    for (int i = 0; i < 8; ++i)
#pragma unroll
      for (int j = 0; j < 8; ++j)
        acc[i][j] = fmaf(a[i], bb[j], acc[i][j]);
  }
}

// ---- K1: fused projection GEMM.  grid (128 Mtiles, 7 jtiles) ----
// jt 0..3 -> v cols jt*128..; jt 4 -> k; jt 5 -> q; jt 6 -> alpha (sigmoid)
__global__ __launch_bounds__(256) void proj_gemm(
    const float* __restrict__ x,
    const float* __restrict__ Wv, const float* __restrict__ bv,
    const float* __restrict__ Wk, const float* __restrict__ bk,
    const float* __restrict__ Wq, const float* __restrict__ bq,
    const float* __restrict__ Wa, const float* __restrict__ ba,
    float* __restrict__ vout, float* __restrict__ kout,
    float* __restrict__ qout, float* __restrict__ aout) {
  __shared__ float lp[32 * 132];
  __shared__ float lv[32 * 132];
  int tid = threadIdx.x;
  int mt = blockIdx.x;
  int jt = blockIdx.y;

  const float* W; const float* bias; float* dst;
  int nout, col0; bool sig = false;
  if (jt < 4)        { W = Wv + (long)jt * 128 * 512; bias = bv + jt * 128; dst = vout; nout = 512; col0 = jt * 128; }
  else if (jt == 4)  { W = Wk; bias = bk; dst = kout; nout = 128; col0 = 0; }
  else if (jt == 5)  { W = Wq; bias = bq; dst = qout; nout = 128; col0 = 0; }
  else               { W = Wa; bias = ba; dst = aout; nout = 128; col0 = 0; sig = true; }

  const float* Xb = x + (long)mt * 128 * 512;
  float acc[8][8] = {};
  int tx = tid & 15, ty = tid >> 4;

  for (int k0 = 0; k0 < 512; k0 += 32) {
    load_trans(lp, Xb, 512, k0, tid);   // lds[k][m] from x[m][k]
    load_trans(lv, W, 512, k0, tid);    // lds[k][n] from W[n][k]
    __syncthreads();
    mm_inner(lp, lv, acc, tx, ty);
    __syncthreads();
  }

#pragma unroll
  for (int i = 0; i < 8; ++i) {
    long r = (long)mt * 128 + tx * 8 + i;
#pragma unroll
    for (int j = 0; j < 8; ++j) {
      int col = ty * 8 + j;
      float z = acc[i][j] + bias[col];
      if (sig) z = 1.f / (1.f + expf(-z));
      dst[r * nout + col0 + col] = z;
    }
  }
}

// ---- K2: per-(c,b,n) cumprod scan; k~ = k/(cp+eps), q~ = q*cp (in place) ----
__global__ __launch_bounds__(256) void scan_cp(const float* __restrict__ a,
                                               float* __restrict__ k,
                                               float* __restrict__ q,
                                               float* __restrict__ cpend) {
  int idx = blockIdx.x * 256 + threadIdx.x;  // 16384 = 16*8*128
  int n = idx & 127;
  int b = (idx >> 7) & 7;
  int c = idx >> 10;
  long base = ((long)c * 1024 + b) * 128 + n;  // row stride per tt = 1024 floats
  float cp = 1.f;
  for (int tt = 0; tt < 128; ++tt) {
    long off = base + (long)tt * 1024;
    float av = fmaxf(a[off], EPSV);
    cp *= av;
    float invp = 1.f / (cp + EPSV);
    k[off] *= invp;
    q[off] *= cp;
  }
  cpend[(c * 8 + b) * 128 + n] = cp;
}

// ---- chunk matmuls: OUT(128 x 128) = P(128x128 over K=128) @ V ----
template <int MODE>
__global__ __launch_bounds__(256) void chunk_mm(const float* __restrict__ P,
                                                const float* __restrict__ V,
                                                float* __restrict__ O,
                                                const float* __restrict__ extra) {
  __shared__ float lp[32 * 132];
  __shared__ float lv[32 * 132];
  int tid = threadIdx.x;
  int cb = blockIdx.x;     // c*8 + b
  int jt = blockIdx.y;
  int c = cb >> 3, b = cb & 7;

  const float* Pb; const float* Vb;
  long pstride, vstride;
  if constexpr (MODE == MODE_A) {        // A[t,s] = sum_n qt[t,n]*kt[s,n]
    Pb = P + ((long)c * 1024 + b) * 128; pstride = 1024;   // qt rows t
    Vb = V + ((long)c * 1024 + b) * 128; vstride = 1024;   // kt rows s
  } else if constexpr (MODE == MODE_Y) { // y[t,d] = sum_s A[t,s]*v[s,d]
    Pb = P + (long)cb * 16384;           pstride = 128;    // A rows t
    Vb = V + ((long)c * 1024 + b) * 512 + jt * 128; vstride = 4096;  // v rows s
  } else if constexpr (MODE == MODE_G) { // G[n,d] = cpend[n]*sum_s kt[s,n]*v[s,d]
    Pb = P + ((long)c * 1024 + b) * 128; pstride = 1024;   // kt rows s (direct: [s][n])
    Vb = V + ((long)c * 1024 + b) * 512 + jt * 128; vstride = 4096;
  } else {                               // y[t,d] += sum_n qt[t,n]*Sp[n,d]
    Pb = P + ((long)c * 1024 + b) * 128; pstride = 1024;   // qt rows t
    Vb = V + (long)cb * 65536 + jt * 128; vstride = 512;   // Sp rows n
  }

  float acc[8][8] = {};
  int tx = tid & 15, ty = tid >> 4;

  for (int k0 = 0; k0 < 128; k0 += 32) {
    if constexpr (MODE == MODE_G) load_direct(lp, Pb, pstride, k0, tid);
    else                          load_trans(lp, Pb, pstride, k0, tid);
    if constexpr (MODE == MODE_A) load_trans(lv, Vb, vstride, k0, tid);
    else                          load_direct(lv, Vb, vstride, k0, tid);
    __syncthreads();
    mm_inner(lp, lv, acc, tx, ty);
    __syncthreads();
  }

  if constexpr (MODE == MODE_A) {
#pragma unroll
    for (int i = 0; i < 8; ++i) {
      int t = tx * 8 + i;
#pragma unroll
      for (int j = 0; j < 8; ++j) {
        int s = ty * 8 + j;
        O[(long)cb * 16384 + t * 128 + s] = (s <= t) ? acc[i][j] : 0.f;
      }
    }
  } else if constexpr (MODE == MODE_Y) {
#pragma unroll
    for (int i = 0; i < 8; ++i) {
      long row = ((long)(c * 128 + tx * 8 + i) * 8 + b) * 512 + jt * 128;
#pragma unroll
      for (int j = 0; j < 8; ++j) O[row + ty * 8 + j] = acc[i][j];
    }
  } else if constexpr (MODE == MODE_G) {
#pragma unroll
    for (int i = 0; i < 8; ++i) {
      int n = tx * 8 + i;
      float ce = extra[cb * 128 + n];
      long row = ((long)cb * 128 + n) * 512 + jt * 128;
#pragma unroll
      for (int j = 0; j < 8; ++j) O[row + ty * 8 + j] = acc[i][j] * ce;
    }
  } else {  // MODE_C: accumulate
#pragma unroll
    for (int i = 0; i < 8; ++i) {
      long row = ((long)(c * 128 + tx * 8 + i) * 8 + b) * 512 + jt * 128;
#pragma unroll
      for (int j = 0; j < 8; ++j) O[row + ty * 8 + j] += acc[i][j];
    }
  }
}

// ---- K4: inter-chunk state scan; overwrites G[c] with S_prev[c] ----
__global__ __launch_bounds__(256) void scan_state(float* __restrict__ G,
                                                  const float* __restrict__ cpend) {
  long e = (long)blockIdx.x * 256 + threadIdx.x;  // 524288 = 8*128*512
  int n = (int)((e >> 9) & 127);
  int b = (int)(e >> 16);
  float S = 0.f;
#pragma unroll
  for (int c = 0; c < 16; ++c) {
    long idx = (long)c * 524288 + e;
    float g = G[idx];
    G[idx] = S;                     // S_prev for chunk c
    float ce = cpend[(c * 8 + b) * 128 + n];
    S = g + S * ce;
  }
}

extern "C" void kernel_launch(void* const* d_in, const int* in_sizes, int n_in,
                              void* d_out, int out_size, void* d_ws, size_t ws_size,
                              hipStream_t stream) {
  const float* x  = (const float*)d_in[0];
  const float* Wv = (const float*)d_in[1];
  const float* bv = (const float*)d_in[2];
  const float* Wk = (const float*)d_in[3];
  const float* bk = (const float*)d_in[4];
  const float* Wq = (const float*)d_in[5];
  const float* bq = (const float*)d_in[6];
  const float* Wa = (const float*)d_in[7];
  const float* ba = (const float*)d_in[8];
  float* out = (float*)d_out;
  float* ws = (float*)d_ws;

  float* v_buf = ws;                      // 8,388,608 floats
  float* k_buf = v_buf + 8388608;         // 2,097,152
  float* q_buf = k_buf + 2097152;         // 2,097,152
  float* a_buf = q_buf + 2097152;         // 2,097,152
  float* A_buf = a_buf;                   // reuse: alpha dead after scan_cp
  float* G_buf = a_buf + 2097152;         // 8,388,608
  float* cpend = G_buf + 8388608;         // 16,384   (total ~92.3 MB)

  proj_gemm<<<dim3(128, 7), 256, 0, stream>>>(x, Wv, bv, Wk, bk, Wq, bq, Wa, ba,
                                              v_buf, k_buf, q_buf, a_buf);
  scan_cp<<<64, 256, 0, stream>>>(a_buf, k_buf, q_buf, cpend);
  chunk_mm<MODE_A><<<dim3(128, 1), 256, 0, stream>>>(q_buf, k_buf, A_buf, nullptr);
  chunk_mm<MODE_Y><<<dim3(128, 4), 256, 0, stream>>>(A_buf, v_buf, out, nullptr);
  chunk_mm<MODE_G><<<dim3(128, 4), 256, 0, stream>>>(k_buf, v_buf, G_buf, cpend);
  scan_state<<<2048, 256, 0, stream>>>(G_buf, cpend);
  chunk_mm<MODE_C><<<dim3(128, 4), 256, 0, stream>>>(q_buf, G_buf, out, nullptr);
}

// Round 2
// 307.955 us; speedup vs baseline: 1.5581x; 1.5581x over previous
//
#include <hip/hip_runtime.h>
#include <math.h>

// GLA forward, chunked. T=2048, B=8, IN=512, DV=512, NK=128, CHUNK=128, NCH=16.
// Round 2: projection GEMM -> bf16 MFMA (m97 structure: global_load_lds w16,
// 128x128 tile, 16x16x32 bf16, 4x4 acc/wave). Downstream unchanged (fp32).

#define EPSV 1e-8f

enum { MODE_A = 0, MODE_Y = 1, MODE_G = 2, MODE_C = 3 };

typedef __bf16 bf16x8 __attribute__((ext_vector_type(8)));
typedef float f32x4 __attribute__((ext_vector_type(4)));

__device__ __forceinline__ void async_copy16(const void* g, void* l) {
  __builtin_amdgcn_global_load_lds(
      (const __attribute__((address_space(1))) void*)g,
      (__attribute__((address_space(3))) void*)l, 16, 0, 0);
}

// ---- fp32 -> bf16 conversion (8 elems/thread) ----
__global__ __launch_bounds__(256) void conv_bf16(const float* __restrict__ src,
                                                 __bf16* __restrict__ dst) {
  long i = ((long)blockIdx.x * 256 + threadIdx.x) * 8;
  float4 f0 = *(const float4*)(src + i);
  float4 f1 = *(const float4*)(src + i + 4);
  bf16x8 h;
  h[0] = (__bf16)f0.x; h[1] = (__bf16)f0.y; h[2] = (__bf16)f0.z; h[3] = (__bf16)f0.w;
  h[4] = (__bf16)f1.x; h[5] = (__bf16)f1.y; h[6] = (__bf16)f1.z; h[7] = (__bf16)f1.w;
  *(bf16x8*)(dst + i) = h;
}

// ---- concat Wv|Wk|Wq|Wa (each [*][512]) into bf16 [896][512] ----
__global__ __launch_bounds__(256) void conv_w(const float* __restrict__ Wv,
                                              const float* __restrict__ Wk,
                                              const float* __restrict__ Wq,
                                              const float* __restrict__ Wa,
                                              __bf16* __restrict__ dst) {
  long i = ((long)blockIdx.x * 256 + threadIdx.x) * 8;  // over 896*512
  int row = (int)(i >> 9);
  int col = (int)(i & 511);
  const float* src;
  if (row < 512)      src = Wv + (long)row * 512 + col;
  else if (row < 640) src = Wk + (long)(row - 512) * 512 + col;
  else if (row < 768) src = Wq + (long)(row - 640) * 512 + col;
  else                src = Wa + (long)(row - 768) * 512 + col;
  float4 f0 = *(const float4*)(src);
  float4 f1 = *(const float4*)(src + 4);
  bf16x8 h;
  h[0] = (__bf16)f0.x; h[1] = (__bf16)f0.y; h[2] = (__bf16)f0.z; h[3] = (__bf16)f0.w;
  h[4] = (__bf16)f1.x; h[5] = (__bf16)f1.y; h[6] = (__bf16)f1.z; h[7] = (__bf16)f1.w;
  *(bf16x8*)(dst + i) = h;
}

// ---- K1: projection GEMM, bf16 MFMA. out[m][n] = sum_k x[m][k]*Wc[n][k] ----
// grid (128 Mtiles, 7 Ntiles of 128). nt 0..3 -> v; 4 -> k; 5 -> q; 6 -> alpha.
__global__ __launch_bounds__(256) void proj_mfma(
    const __bf16* __restrict__ xb, const __bf16* __restrict__ wcat,
    const float* __restrict__ bv, const float* __restrict__ bk,
    const float* __restrict__ bq, const float* __restrict__ ba,
    float* __restrict__ vout, float* __restrict__ kout,
    float* __restrict__ qout, float* __restrict__ aout) {
  __shared__ __bf16 a_sm[128 * 32];
  __shared__ __bf16 b_sm[128 * 32];
  int tid = threadIdx.x;
  int lane = tid & 63, wave = tid >> 6;
  int mt = blockIdx.x, nt = blockIdx.y;
  int wr = wave >> 1, wcol = wave & 1;

  const __bf16* xtile = xb + (long)mt * 128 * 512;
  const __bf16* wtile = wcat + (long)nt * 128 * 512;

  f32x4 acc[4][4] = {};
  int lr = lane >> 2, lc = lane & 3;   // staging: row-in-chunk, 16B col chunk
  int l15 = lane & 15, qd = lane >> 4;

  for (int k0 = 0; k0 < 512; k0 += 32) {
#pragma unroll
    for (int h = 0; h < 2; ++h) {
      int q = wave * 2 + h;            // 1KB chunk = 16 rows of the 128x32 tile
      int row = q * 16 + lr;
      async_copy16(xtile + (long)row * 512 + k0 + lc * 8, &a_sm[q * 512]);
      async_copy16(wtile + (long)row * 512 + k0 + lc * 8, &b_sm[q * 512]);
    }
    __syncthreads();
    bf16x8 af[4], bfr[4];
#pragma unroll
    for (int t = 0; t < 4; ++t) {
      af[t]  = *(const bf16x8*)&a_sm[(wr * 64 + t * 16 + l15) * 32 + qd * 8];
      bfr[t] = *(const bf16x8*)&b_sm[(wcol * 64 + t * 16 + l15) * 32 + qd * 8];
    }
#pragma unroll
    for (int i = 0; i < 4; ++i)
#pragma unroll
      for (int j = 0; j < 4; ++j)
        acc[i][j] = __builtin_amdgcn_mfma_f32_16x16x32_bf16(af[i], bfr[j], acc[i][j], 0, 0, 0);
    __syncthreads();
  }

  const float* bias; float* dst; int nout; int col0; bool sig = false;
  if (nt < 4)       { bias = bv + nt * 128; dst = vout; nout = 512; col0 = nt * 128; }
  else if (nt == 4) { bias = bk; dst = kout; nout = 128; col0 = 0; }
  else if (nt == 5) { bias = bq; dst = qout; nout = 128; col0 = 0; }
  else              { bias = ba; dst = aout; nout = 128; col0 = 0; sig = true; }

#pragma unroll
  for (int i = 0; i < 4; ++i) {
#pragma unroll
    for (int j = 0; j < 4; ++j) {
      int col = wcol * 64 + j * 16 + l15;
      float bz = bias[col];
#pragma unroll
      for (int r = 0; r < 4; ++r) {
        int row = wr * 64 + i * 16 + qd * 4 + r;
        float z = acc[i][j][r] + bz;
        if (sig) z = 1.f / (1.f + __expf(-z));
        dst[((long)mt * 128 + row) * nout + col0 + col] = z;
      }
    }
  }
}

// ---- K2: per-(c,b,n) cumprod scan; k~ = k/(cp+eps), q~ = q*cp (in place) ----
__global__ __launch_bounds__(256) void scan_cp(const float* __restrict__ a,
                                               float* __restrict__ k,
                                               float* __restrict__ q,
                                               float* __restrict__ cpend) {
  int idx = blockIdx.x * 256 + threadIdx.x;  // 16384 = 16*8*128
  int n = idx & 127;
  int b = (idx >> 7) & 7;
  int c = idx >> 10;
  long base = ((long)c * 1024 + b) * 128 + n;
  float cp = 1.f;
  for (int tt = 0; tt < 128; ++tt) {
    long off = base + (long)tt * 1024;
    float av = fmaxf(a[off], EPSV);
    cp *= av;
    float invp = 1.f / (cp + EPSV);
    k[off] *= invp;
    q[off] *= cp;
  }
  cpend[(c * 8 + b) * 128 + n] = cp;
}

// ---- fp32 LDS-tiled chunk matmuls (unchanged from round 1) ----
__device__ __forceinline__ void load_direct(float* lds, const float* __restrict__ src,
                                            long stride, int k0, int tid) {
#pragma unroll
  for (int it = 0; it < 4; ++it) {
    int f = tid + 256 * it;
    int kk = f >> 5;
    int c4 = f & 31;
    float4 val = *(const float4*)(src + (long)(k0 + kk) * stride + (c4 << 2));
    *(float4*)(lds + kk * 132 + (c4 << 2)) = val;
  }
}

__device__ __forceinline__ void load_trans(float* lds, const float* __restrict__ src,
                                           long stride, int k0, int tid) {
#pragma unroll
  for (int it = 0; it < 4; ++it) {
    int f = tid + 256 * it;
    int m = f >> 3;
    int kq = f & 7;
    float4 val = *(const float4*)(src + (long)m * stride + k0 + (kq << 2));
    lds[(kq * 4 + 0) * 132 + m] = val.x;
    lds[(kq * 4 + 1) * 132 + m] = val.y;
    lds[(kq * 4 + 2) * 132 + m] = val.z;
    lds[(kq * 4 + 3) * 132 + m] = val.w;
  }
}

__device__ __forceinline__ void mm_inner(const float* lp, const float* lv,
                                         float acc[8][8], int tx, int ty) {
#pragma unroll 8
  for (int kk = 0; kk < 32; ++kk) {
    const float* lpr = lp + kk * 132;
    const float* lvr = lv + kk * 132;
    float a[8], bb[8];
    *(float4*)(a)      = *(const float4*)(lpr + tx * 8);
    *(float4*)(a + 4)  = *(const float4*)(lpr + tx * 8 + 4);
    *(float4*)(bb)     = *(const float4*)(lvr + ty * 8);
    *(float4*)(bb + 4) = *(const float4*)(lvr + ty * 8 + 4);
#pragma unroll
    for (int i = 0; i < 8; ++i)
#pragma unroll
      for (int j = 0; j < 8; ++j)
        acc[i][j] = fmaf(a[i], bb[j], acc[i][j]);
  }
}

template <int MODE>
__global__ __launch_bounds__(256) void chunk_mm(const float* __restrict__ P,
                                                const float* __restrict__ V,
                                                float* __restrict__ O,
                                                const float* __restrict__ extra) {
  __shared__ float lp[32 * 132];
  __shared__ float lv[32 * 132];
  int tid = threadIdx.x;
  int cb = blockIdx.x;
  int jt = blockIdx.y;
  int c = cb >> 3, b = cb & 7;

  const float* Pb; const float* Vb;
  long pstride, vstride;
  if constexpr (MODE == MODE_A) {
    Pb = P + ((long)c * 1024 + b) * 128; pstride = 1024;
    Vb = V + ((long)c * 1024 + b) * 128; vstride = 1024;
  } else if constexpr (MODE == MODE_Y) {
    Pb = P + (long)cb * 16384;           pstride = 128;
    Vb = V + ((long)c * 1024 + b) * 512 + jt * 128; vstride = 4096;
  } else if constexpr (MODE == MODE_G) {
    Pb = P + ((long)c * 1024 + b) * 128; pstride = 1024;
    Vb = V + ((long)c * 1024 + b) * 512 + jt * 128; vstride = 4096;
  } else {
    Pb = P + ((long)c * 1024 + b) * 128; pstride = 1024;
    Vb = V + (long)cb * 65536 + jt * 128; vstride = 512;
  }

  float acc[8][8] = {};
  int tx = tid & 15, ty = tid >> 4;

  for (int k0 = 0; k0 < 128; k0 += 32) {
    if constexpr (MODE == MODE_G) load_direct(lp, Pb, pstride, k0, tid);
    else                          load_trans(lp, Pb, pstride, k0, tid);
    if constexpr (MODE == MODE_A) load_trans(lv, Vb, vstride, k0, tid);
    else                          load_direct(lv, Vb, vstride, k0, tid);
    __syncthreads();
    mm_inner(lp, lv, acc, tx, ty);
    __syncthreads();
  }

  if constexpr (MODE == MODE_A) {
#pragma unroll
    for (int i = 0; i < 8; ++i) {
      int t = tx * 8 + i;
#pragma unroll
      for (int j = 0; j < 8; ++j) {
        int s = ty * 8 + j;
        O[(long)cb * 16384 + t * 128 + s] = (s <= t) ? acc[i][j] : 0.f;
      }
    }
  } else if constexpr (MODE == MODE_Y) {
#pragma unroll
    for (int i = 0; i < 8; ++i) {
      long row = ((long)(c * 128 + tx * 8 + i) * 8 + b) * 512 + jt * 128;
#pragma unroll
      for (int j = 0; j < 8; ++j) O[row + ty * 8 + j] = acc[i][j];
    }
  } else if constexpr (MODE == MODE_G) {
#pragma unroll
    for (int i = 0; i < 8; ++i) {
      int n = tx * 8 + i;
      float ce = extra[cb * 128 + n];
      long row = ((long)cb * 128 + n) * 512 + jt * 128;
#pragma unroll
      for (int j = 0; j < 8; ++j) O[row + ty * 8 + j] = acc[i][j] * ce;
    }
  } else {
#pragma unroll
    for (int i = 0; i < 8; ++i) {
      long row = ((long)(c * 128 + tx * 8 + i) * 8 + b) * 512 + jt * 128;
#pragma unroll
      for (int j = 0; j < 8; ++j) O[row + ty * 8 + j] += acc[i][j];
    }
  }
}

// ---- K4: inter-chunk state scan; overwrites G[c] with S_prev[c] ----
__global__ __launch_bounds__(256) void scan_state(float* __restrict__ G,
                                                  const float* __restrict__ cpend) {
  long e = (long)blockIdx.x * 256 + threadIdx.x;  // 524288 = 8*128*512
  int n = (int)((e >> 9) & 127);
  int b = (int)(e >> 16);
  float S = 0.f;
#pragma unroll
  for (int c = 0; c < 16; ++c) {
    long idx = (long)c * 524288 + e;
    float g = G[idx];
    G[idx] = S;
    float ce = cpend[(c * 8 + b) * 128 + n];
    S = g + S * ce;
  }
}

extern "C" void kernel_launch(void* const* d_in, const int* in_sizes, int n_in,
                              void* d_out, int out_size, void* d_ws, size_t ws_size,
                              hipStream_t stream) {
  const float* x  = (const float*)d_in[0];
  const float* Wv = (const float*)d_in[1];
  const float* bv = (const float*)d_in[2];
  const float* Wk = (const float*)d_in[3];
  const float* bk = (const float*)d_in[4];
  const float* Wq = (const float*)d_in[5];
  const float* bq = (const float*)d_in[6];
  const float* Wa = (const float*)d_in[7];
  const float* ba = (const float*)d_in[8];
  float* out = (float*)d_out;
  float* ws = (float*)d_ws;

  float* v_buf = ws;                      // 8,388,608 floats
  float* k_buf = v_buf + 8388608;         // 2,097,152
  float* q_buf = k_buf + 2097152;         // 2,097,152
  float* a_buf = q_buf + 2097152;         // 2,097,152
  float* A_buf = a_buf;                   // reuse: alpha dead after scan_cp
  float* G_buf = a_buf + 2097152;         // 8,388,608
  float* cpend = G_buf + 8388608;         // 16,384   (total ~92.3 MB)
  // x_bf16 + Wc overlay the G_buf region (dead until chunk_mm<MODE_G>)
  __bf16* x_bf16 = (__bf16*)G_buf;              // 8,388,608 bf16
  __bf16* Wcat   = (__bf16*)(G_buf + 4194304);  // 458,752 bf16

  conv_bf16<<<4096, 256, 0, stream>>>(x, x_bf16);           // 8,388,608 / 8 / 256
  conv_w<<<224, 256, 0, stream>>>(Wv, Wk, Wq, Wa, Wcat);    // 458,752 / 8 / 256
  proj_mfma<<<dim3(128, 7), 256, 0, stream>>>(x_bf16, Wcat, bv, bk, bq, ba,
                                              v_buf, k_buf, q_buf, a_buf);
  scan_cp<<<64, 256, 0, stream>>>(a_buf, k_buf, q_buf, cpend);
  chunk_mm<MODE_A><<<dim3(128, 1), 256, 0, stream>>>(q_buf, k_buf, A_buf, nullptr);
  chunk_mm<MODE_Y><<<dim3(128, 4), 256, 0, stream>>>(A_buf, v_buf, out, nullptr);
  chunk_mm<MODE_G><<<dim3(128, 4), 256, 0, stream>>>(k_buf, v_buf, G_buf, cpend);
  scan_state<<<2048, 256, 0, stream>>>(G_buf, cpend);
  chunk_mm<MODE_C><<<dim3(128, 4), 256, 0, stream>>>(q_buf, G_buf, out, nullptr);
}

// Round 3
// 220.619 us; speedup vs baseline: 2.1748x; 1.3959x over previous
//
#include <hip/hip_runtime.h>

// GLA forward, chunked. T=2048, B=8, IN=512, DV=512, NK=128, CHUNK=128, NCH=16.
// Round 3: all matmuls bf16 MFMA. y computed transposed (y^T[d,t]) so all
// operands are natural K-contiguous; A fused into ymm via LDS (never hits HBM).
//
// Layouts (cb = c*8+b):
//   v/k/q/a fp32 natural [r][*], r = t_glob*8+b
//   qb/kb  bf16 natural [r][n]
//   kt     bf16 [cb*128 + n][s]
//   vt     bf16 [cb*512 + d][s]
//   Gt     fp32 [cb*512 + d][n]   (scan input)
//   St     bf16 [cb*512 + d][n]   (S_prev per chunk)

#define EPSV 1e-8f

typedef __bf16 bf16x8 __attribute__((ext_vector_type(8)));
typedef float f32x4 __attribute__((ext_vector_type(4)));

__device__ __forceinline__ void async_copy16(const void* g, void* l) {
  __builtin_amdgcn_global_load_lds(
      (const __attribute__((address_space(1))) void*)g,
      (__attribute__((address_space(3))) void*)l, 16, 0, 0);
}

// ---- fp32 -> bf16 conversion (8 elems/thread) ----
__global__ __launch_bounds__(256) void conv_bf16(const float* __restrict__ src,
                                                 __bf16* __restrict__ dst) {
  long i = ((long)blockIdx.x * 256 + threadIdx.x) * 8;
  float4 f0 = *(const float4*)(src + i);
  float4 f1 = *(const float4*)(src + i + 4);
  bf16x8 h;
  h[0] = (__bf16)f0.x; h[1] = (__bf16)f0.y; h[2] = (__bf16)f0.z; h[3] = (__bf16)f0.w;
  h[4] = (__bf16)f1.x; h[5] = (__bf16)f1.y; h[6] = (__bf16)f1.z; h[7] = (__bf16)f1.w;
  *(bf16x8*)(dst + i) = h;
}

// ---- concat Wv|Wk|Wq|Wa into bf16 [896][512] ----
__global__ __launch_bounds__(256) void conv_w(const float* __restrict__ Wv,
                                              const float* __restrict__ Wk,
                                              const float* __restrict__ Wq,
                                              const float* __restrict__ Wa,
                                              __bf16* __restrict__ dst) {
  long i = ((long)blockIdx.x * 256 + threadIdx.x) * 8;
  int row = (int)(i >> 9);
  int col = (int)(i & 511);
  const float* src;
  if (row < 512)      src = Wv + (long)row * 512 + col;
  else if (row < 640) src = Wk + (long)(row - 512) * 512 + col;
  else if (row < 768) src = Wq + (long)(row - 640) * 512 + col;
  else                src = Wa + (long)(row - 768) * 512 + col;
  float4 f0 = *(const float4*)(src);
  float4 f1 = *(const float4*)(src + 4);
  bf16x8 h;
  h[0] = (__bf16)f0.x; h[1] = (__bf16)f0.y; h[2] = (__bf16)f0.z; h[3] = (__bf16)f0.w;
  h[4] = (__bf16)f1.x; h[5] = (__bf16)f1.y; h[6] = (__bf16)f1.z; h[7] = (__bf16)f1.w;
  *(bf16x8*)(dst + i) = h;
}

// ---- K1: projection GEMM, bf16 MFMA (m97 structure, unchanged) ----
__global__ __launch_bounds__(256) void proj_mfma(
    const __bf16* __restrict__ xb, const __bf16* __restrict__ wcat,
    const float* __restrict__ bv, const float* __restrict__ bk,
    const float* __restrict__ bq, const float* __restrict__ ba,
    float* __restrict__ vout, float* __restrict__ kout,
    float* __restrict__ qout, float* __restrict__ aout) {
  __shared__ __bf16 a_sm[128 * 32];
  __shared__ __bf16 b_sm[128 * 32];
  int tid = threadIdx.x;
  int lane = tid & 63, wave = tid >> 6;
  int mt = blockIdx.x, nt = blockIdx.y;
  int wr = wave >> 1, wcol = wave & 1;

  const __bf16* xtile = xb + (long)mt * 128 * 512;
  const __bf16* wtile = wcat + (long)nt * 128 * 512;

  f32x4 acc[4][4] = {};
  int lr = lane >> 2, lc = lane & 3;
  int l15 = lane & 15, qd = lane >> 4;

  for (int k0 = 0; k0 < 512; k0 += 32) {
#pragma unroll
    for (int h = 0; h < 2; ++h) {
      int q = wave * 2 + h;
      int row = q * 16 + lr;
      async_copy16(xtile + (long)row * 512 + k0 + lc * 8, &a_sm[q * 512]);
      async_copy16(wtile + (long)row * 512 + k0 + lc * 8, &b_sm[q * 512]);
    }
    __syncthreads();
    bf16x8 af[4], bfr[4];
#pragma unroll
    for (int t = 0; t < 4; ++t) {
      af[t]  = *(const bf16x8*)&a_sm[(wr * 64 + t * 16 + l15) * 32 + qd * 8];
      bfr[t] = *(const bf16x8*)&b_sm[(wcol * 64 + t * 16 + l15) * 32 + qd * 8];
    }
#pragma unroll
    for (int i = 0; i < 4; ++i)
#pragma unroll
      for (int j = 0; j < 4; ++j)
        acc[i][j] = __builtin_amdgcn_mfma_f32_16x16x32_bf16(af[i], bfr[j], acc[i][j], 0, 0, 0);
    __syncthreads();
  }

  const float* bias; float* dst; int nout; int col0; bool sig = false;
  if (nt < 4)       { bias = bv + nt * 128; dst = vout; nout = 512; col0 = nt * 128; }
  else if (nt == 4) { bias = bk; dst = kout; nout = 128; col0 = 0; }
  else if (nt == 5) { bias = bq; dst = qout; nout = 128; col0 = 0; }
  else              { bias = ba; dst = aout; nout = 128; col0 = 0; sig = true; }

#pragma unroll
  for (int i = 0; i < 4; ++i) {
#pragma unroll
    for (int j = 0; j < 4; ++j) {
      int col = wcol * 64 + j * 16 + l15;
      float bz = bias[col];
#pragma unroll
      for (int r = 0; r < 4; ++r) {
        int row = wr * 64 + i * 16 + qd * 4 + r;
        float z = acc[i][j][r] + bz;
        if (sig) z = 1.f / (1.f + __expf(-z));
        dst[((long)mt * 128 + row) * nout + col0 + col] = z;
      }
    }
  }
}

// ---- vtrans: v fp32 natural -> vt bf16 [cb*512+d][s], one thread per row ----
__global__ __launch_bounds__(256) void vtrans(const float* __restrict__ v,
                                              __bf16* __restrict__ vt) {
  int idx = blockIdx.x * 256 + threadIdx.x;  // 65536 = 128 cb * 512 d
  int d = idx & 511, cb = idx >> 9;
  int c = cb >> 3, b = cb & 7;
  long base = ((long)c * 1024 + b) * 512 + d;
  __bf16 buf[128];
#pragma unroll
  for (int t = 0; t < 128; ++t) buf[t] = (__bf16)v[base + (long)t * 4096];
  __bf16* dst = vt + ((long)cb * 512 + d) * 128;
#pragma unroll
  for (int i = 0; i < 16; ++i) {
    bf16x8 h;
#pragma unroll
    for (int j = 0; j < 8; ++j) h[j] = buf[i * 8 + j];
    *(bf16x8*)(dst + i * 8) = h;
  }
}

// ---- scan_cp: cumprod; emits qb/kb bf16 natural, kt bf16 transposed, cpend ----
__global__ __launch_bounds__(256) void scan_cp(const float* __restrict__ a,
                                               const float* __restrict__ k,
                                               const float* __restrict__ q,
                                               __bf16* __restrict__ kb,
                                               __bf16* __restrict__ qb,
                                               __bf16* __restrict__ kt,
                                               float* __restrict__ cpend) {
  int idx = blockIdx.x * 256 + threadIdx.x;  // 16384 = 16*8*128
  int n = idx & 127;
  int b = (idx >> 7) & 7;
  int c = idx >> 10;
  long base = ((long)c * 1024 + b) * 128 + n;
  float cp = 1.f;
  __bf16 ktbuf[128];
#pragma unroll
  for (int tt = 0; tt < 128; ++tt) {
    long off = base + (long)tt * 1024;
    float av = fmaxf(a[off], EPSV);
    cp *= av;
    float kk = k[off] / (cp + EPSV);
    float qq = q[off] * cp;
    kb[off] = (__bf16)kk;
    qb[off] = (__bf16)qq;
    ktbuf[tt] = (__bf16)kk;
  }
  cpend[(c * 8 + b) * 128 + n] = cp;
  __bf16* dst = kt + ((long)((c * 8 + b) * 128 + n)) * 128;
#pragma unroll
  for (int i = 0; i < 16; ++i) {
    bf16x8 h;
#pragma unroll
    for (int j = 0; j < 8; ++j) h[j] = ktbuf[i * 8 + j];
    *(bf16x8*)(dst + i * 8) = h;
  }
}

// ---- gmm: Gt[d,n] = cpend[n] * sum_s vt[d,s]*kt[n,s].  grid 512 = cb*4+dt ----
__global__ __launch_bounds__(256) void gmm(const __bf16* __restrict__ vt,
                                           const __bf16* __restrict__ kt,
                                           const float* __restrict__ cpend,
                                           float* __restrict__ Gt) {
  int tid = threadIdx.x, lane = tid & 63, wave = tid >> 6;
  int wr = wave >> 1, wc = wave & 1;
  int l15 = lane & 15, qd = lane >> 4;
  int cb = blockIdx.x >> 2, dt = blockIdx.x & 3;
  const __bf16* vbase = vt + ((long)cb * 512 + dt * 128) * 128;
  const __bf16* kbase = kt + (long)cb * 16384;
  f32x4 acc[4][4] = {};
#pragma unroll
  for (int kk = 0; kk < 4; ++kk) {
    int k0 = kk * 32;
    bf16x8 af[4], bfr[4];
#pragma unroll
    for (int i = 0; i < 4; ++i)
      af[i] = *(const bf16x8*)(vbase + (long)(wr * 64 + i * 16 + l15) * 128 + k0 + qd * 8);
#pragma unroll
    for (int j = 0; j < 4; ++j)
      bfr[j] = *(const bf16x8*)(kbase + (long)(wc * 64 + j * 16 + l15) * 128 + k0 + qd * 8);
#pragma unroll
    for (int i = 0; i < 4; ++i)
#pragma unroll
      for (int j = 0; j < 4; ++j)
        acc[i][j] = __builtin_amdgcn_mfma_f32_16x16x32_bf16(af[i], bfr[j], acc[i][j], 0, 0, 0);
  }
  float ce[4];
#pragma unroll
  for (int j = 0; j < 4; ++j) ce[j] = cpend[cb * 128 + wc * 64 + j * 16 + l15];
#pragma unroll
  for (int i = 0; i < 4; ++i)
#pragma unroll
    for (int j = 0; j < 4; ++j) {
      int col = wc * 64 + j * 16 + l15;
#pragma unroll
      for (int r = 0; r < 4; ++r) {
        int row = wr * 64 + i * 16 + qd * 4 + r;
        Gt[((long)cb * 512 + dt * 128 + row) * 128 + col] = acc[i][j][r] * ce[j];
      }
    }
}

// ---- scan_state: fp32 scan over chunks on Gt; emits St bf16 (S_prev) ----
__global__ __launch_bounds__(256) void scan_state(const float* __restrict__ Gt,
                                                  const float* __restrict__ cpend,
                                                  __bf16* __restrict__ St) {
  long e = (long)blockIdx.x * 256 + threadIdx.x;  // 524288 = 8b*512d*128n
  int n = (int)(e & 127);
  int b = (int)(e >> 16);
  float S = 0.f;
#pragma unroll
  for (int c = 0; c < 16; ++c) {
    long idx = (long)c * 524288 + e;
    float g = Gt[idx];
    St[idx] = (__bf16)S;
    S = g + S * cpend[(c * 8 + b) * 128 + n];
  }
}

// ---- ymm: y^T[d,t] = sum_s vt[d,s]*A[t,s] + sum_n St[d,n]*qb[t,n] ----
// A = qb kb^T masked, computed per block into LDS (bf16). grid 512 = cb*4+dt.
__global__ __launch_bounds__(256) void ymm(const __bf16* __restrict__ qb,
                                           const __bf16* __restrict__ kb,
                                           const __bf16* __restrict__ vt,
                                           const __bf16* __restrict__ St,
                                           float* __restrict__ out) {
  __shared__ __bf16 A_lds[128 * 136];
  int tid = threadIdx.x, lane = tid & 63, wave = tid >> 6;
  int wr = wave >> 1, wc = wave & 1;
  int l15 = lane & 15, qd = lane >> 4;
  int cb = blockIdx.x >> 2, dt = blockIdx.x & 3;
  int c = cb >> 3, b = cb & 7;
  const __bf16* qbase = qb + ((long)c * 1024 + b) * 128;
  const __bf16* kbase = kb + ((long)c * 1024 + b) * 128;

  // phase 1: A[t,s], masked, -> LDS bf16
  {
    f32x4 accA[4][4] = {};
#pragma unroll
    for (int kk = 0; kk < 4; ++kk) {
      int k0 = kk * 32;
      bf16x8 af[4], bfr[4];
#pragma unroll
      for (int i = 0; i < 4; ++i)
        af[i] = *(const bf16x8*)(qbase + (long)(wr * 64 + i * 16 + l15) * 1024 + k0 + qd * 8);
#pragma unroll
      for (int j = 0; j < 4; ++j)
        bfr[j] = *(const bf16x8*)(kbase + (long)(wc * 64 + j * 16 + l15) * 1024 + k0 + qd * 8);
#pragma unroll
      for (int i = 0; i < 4; ++i)
#pragma unroll
        for (int j = 0; j < 4; ++j)
          accA[i][j] = __builtin_amdgcn_mfma_f32_16x16x32_bf16(af[i], bfr[j], accA[i][j], 0, 0, 0);
    }
#pragma unroll
    for (int i = 0; i < 4; ++i)
#pragma unroll
      for (int j = 0; j < 4; ++j) {
        int s = wc * 64 + j * 16 + l15;
#pragma unroll
        for (int r = 0; r < 4; ++r) {
          int t = wr * 64 + i * 16 + qd * 4 + r;
          A_lds[t * 136 + s] = (s <= t) ? (__bf16)accA[i][j][r] : (__bf16)0.f;
        }
      }
  }
  __syncthreads();

  // phase 2: y^T accumulation
  f32x4 acc[4][4] = {};
  const __bf16* vbase = vt + ((long)cb * 512 + dt * 128) * 128;
  const __bf16* sbase = St + ((long)cb * 512 + dt * 128) * 128;
#pragma unroll
  for (int kk = 0; kk < 4; ++kk) {
    int k0 = kk * 32;
    bf16x8 af[4], bfr[4];
#pragma unroll
    for (int i = 0; i < 4; ++i)
      af[i] = *(const bf16x8*)(vbase + (long)(wr * 64 + i * 16 + l15) * 128 + k0 + qd * 8);
#pragma unroll
    for (int j = 0; j < 4; ++j)
      bfr[j] = *(const bf16x8*)&A_lds[(wc * 64 + j * 16 + l15) * 136 + k0 + qd * 8];
#pragma unroll
    for (int i = 0; i < 4; ++i)
#pragma unroll
      for (int j = 0; j < 4; ++j)
        acc[i][j] = __builtin_amdgcn_mfma_f32_16x16x32_bf16(af[i], bfr[j], acc[i][j], 0, 0, 0);
  }
#pragma unroll
  for (int kk = 0; kk < 4; ++kk) {
    int k0 = kk * 32;
    bf16x8 af[4], bfr[4];
#pragma unroll
    for (int i = 0; i < 4; ++i)
      af[i] = *(const bf16x8*)(sbase + (long)(wr * 64 + i * 16 + l15) * 128 + k0 + qd * 8);
#pragma unroll
    for (int j = 0; j < 4; ++j)
      bfr[j] = *(const bf16x8*)(qbase + (long)(wc * 64 + j * 16 + l15) * 1024 + k0 + qd * 8);
#pragma unroll
    for (int i = 0; i < 4; ++i)
#pragma unroll
      for (int j = 0; j < 4; ++j)
        acc[i][j] = __builtin_amdgcn_mfma_f32_16x16x32_bf16(af[i], bfr[j], acc[i][j], 0, 0, 0);
  }

  // epilogue: out[(c*128+t)*8+b][dt*128 + d], contiguous float4 per lane
#pragma unroll
  for (int i = 0; i < 4; ++i)
#pragma unroll
    for (int j = 0; j < 4; ++j) {
      int colt = wc * 64 + j * 16 + l15;
      long addr = ((long)(c * 128 + colt) * 8 + b) * 512 + dt * 128 + wr * 64 + i * 16 + qd * 4;
      *(float4*)(out + addr) = *(float4*)&acc[i][j];
    }
}

extern "C" void kernel_launch(void* const* d_in, const int* in_sizes, int n_in,
                              void* d_out, int out_size, void* d_ws, size_t ws_size,
                              hipStream_t stream) {
  const float* x  = (const float*)d_in[0];
  const float* Wv = (const float*)d_in[1];
  const float* bv = (const float*)d_in[2];
  const float* Wk = (const float*)d_in[3];
  const float* bk = (const float*)d_in[4];
  const float* Wq = (const float*)d_in[5];
  const float* bq = (const float*)d_in[6];
  const float* Wa = (const float*)d_in[7];
  const float* ba = (const float*)d_in[8];
  float* out = (float*)d_out;
  float* ws = (float*)d_ws;

  // float offsets; total 22,036,480 floats = 88.1 MB
  float*  v_buf = ws;                          // 8,388,608
  float*  k_buf = ws + 8388608;                // 2,097,152
  float*  q_buf = ws + 10485760;               // 2,097,152
  float*  a_buf = ws + 12582912;               // 2,097,152
  __bf16* qb    = (__bf16*)(ws + 14680064);    // 2,097,152 bf16
  __bf16* kb    = (__bf16*)(ws + 15728640);    // 2,097,152 bf16
  __bf16* kt    = (__bf16*)(ws + 16777216);    // 2,097,152 bf16
  __bf16* vt    = (__bf16*)(ws + 17825792);    // 8,388,608 bf16
  float*  cpend = ws + 22020096;               // 16,384
  float*  Gt    = ws;                          // overlays v_buf (dead after vtrans)
  __bf16* St    = (__bf16*)(ws + 8388608);     // overlays k/q_buf (dead after scan_cp)
  __bf16* xb    = vt;                          // dead before vtrans writes vt
  __bf16* Wcat  = kt;                          // dead before scan_cp writes kt

  conv_bf16<<<4096, 256, 0, stream>>>(x, xb);
  conv_w<<<224, 256, 0, stream>>>(Wv, Wk, Wq, Wa, Wcat);
  proj_mfma<<<dim3(128, 7), 256, 0, stream>>>(xb, Wcat, bv, bk, bq, ba,
                                              v_buf, k_buf, q_buf, a_buf);
  vtrans<<<256, 256, 0, stream>>>(v_buf, vt);
  scan_cp<<<64, 256, 0, stream>>>(a_buf, k_buf, q_buf, kb, qb, kt, cpend);
  gmm<<<512, 256, 0, stream>>>(vt, kt, cpend, Gt);
  scan_state<<<2048, 256, 0, stream>>>(Gt, cpend, St);
  ymm<<<512, 256, 0, stream>>>(qb, kb, vt, St, out);
}

// Round 4
// 200.180 us; speedup vs baseline: 2.3969x; 1.1021x over previous
//
#include <hip/hip_runtime.h>

// GLA forward, chunked. T=2048, B=8, IN=512, DV=512, NK=128, CHUNK=128, NCH=16.
// Round 4: eliminate fp32 intermediate round-trips. proj writes vt (bf16,
// transposed via LDS), k/q bf16 natural, alpha fp32 (precision-critical).
// Gt bf16. vtrans kernel deleted.
//
// Layouts (cb = c*8+b, r = t_glob*8+b):
//   a_buf  fp32 [r][128]
//   k_raw/q_raw bf16 [r][128]
//   qb/kbs bf16 [r][128]          (q~ = q*cp, k~ = k/(cp+eps))
//   kt     bf16 [cb*128 + n][s]   (k~ transposed)
//   vt     bf16 [cb*512 + d][s]
//   Gt     bf16 [cb*512 + d][n]   (scan input, overlays xb)
//   St     bf16 [cb*512 + d][n]   (S_prev per chunk)

#define EPSV 1e-8f

typedef __bf16 bf16x8 __attribute__((ext_vector_type(8)));
typedef float f32x4 __attribute__((ext_vector_type(4)));

__device__ __forceinline__ void async_copy16(const void* g, void* l) {
  __builtin_amdgcn_global_load_lds(
      (const __attribute__((address_space(1))) void*)g,
      (__attribute__((address_space(3))) void*)l, 16, 0, 0);
}

// ---- fp32 -> bf16 conversion (8 elems/thread) ----
__global__ __launch_bounds__(256) void conv_bf16(const float* __restrict__ src,
                                                 __bf16* __restrict__ dst) {
  long i = ((long)blockIdx.x * 256 + threadIdx.x) * 8;
  float4 f0 = *(const float4*)(src + i);
  float4 f1 = *(const float4*)(src + i + 4);
  bf16x8 h;
  h[0] = (__bf16)f0.x; h[1] = (__bf16)f0.y; h[2] = (__bf16)f0.z; h[3] = (__bf16)f0.w;
  h[4] = (__bf16)f1.x; h[5] = (__bf16)f1.y; h[6] = (__bf16)f1.z; h[7] = (__bf16)f1.w;
  *(bf16x8*)(dst + i) = h;
}

// ---- concat Wv|Wk|Wq|Wa into bf16 [896][512] ----
__global__ __launch_bounds__(256) void conv_w(const float* __restrict__ Wv,
                                              const float* __restrict__ Wk,
                                              const float* __restrict__ Wq,
                                              const float* __restrict__ Wa,
                                              __bf16* __restrict__ dst) {
  long i = ((long)blockIdx.x * 256 + threadIdx.x) * 8;
  int row = (int)(i >> 9);
  int col = (int)(i & 511);
  const float* src;
  if (row < 512)      src = Wv + (long)row * 512 + col;
  else if (row < 640) src = Wk + (long)(row - 512) * 512 + col;
  else if (row < 768) src = Wq + (long)(row - 640) * 512 + col;
  else                src = Wa + (long)(row - 768) * 512 + col;
  float4 f0 = *(const float4*)(src);
  float4 f1 = *(const float4*)(src + 4);
  bf16x8 h;
  h[0] = (__bf16)f0.x; h[1] = (__bf16)f0.y; h[2] = (__bf16)f0.z; h[3] = (__bf16)f0.w;
  h[4] = (__bf16)f1.x; h[5] = (__bf16)f1.y; h[6] = (__bf16)f1.z; h[7] = (__bf16)f1.w;
  *(bf16x8*)(dst + i) = h;
}

// ---- K1: projection GEMM, bf16 MFMA. grid (128 Mtiles, 7 Ntiles) ----
// nt 0..3 -> vt (bf16, LDS-transposed); 4 -> k_raw; 5 -> q_raw; 6 -> alpha fp32.
__global__ __launch_bounds__(256) void proj_mfma(
    const __bf16* __restrict__ xb, const __bf16* __restrict__ wcat,
    const float* __restrict__ bv, const float* __restrict__ bk,
    const float* __restrict__ bq, const float* __restrict__ ba,
    __bf16* __restrict__ vt, __bf16* __restrict__ kout,
    __bf16* __restrict__ qout, float* __restrict__ aout) {
  // 34816 B: staging (16 KB) first, transpose buffer reuses whole block
  __shared__ __attribute__((aligned(16))) char smem[128 * 136 * 2];
  __bf16* a_sm = (__bf16*)smem;
  __bf16* b_sm = a_sm + 128 * 32;
  __bf16* tr   = (__bf16*)smem;      // reused after K-loop (post-barrier)

  int tid = threadIdx.x;
  int lane = tid & 63, wave = tid >> 6;
  int mt = blockIdx.x, nt = blockIdx.y;
  int wr = wave >> 1, wcol = wave & 1;

  const __bf16* xtile = xb + (long)mt * 128 * 512;
  const __bf16* wtile = wcat + (long)nt * 128 * 512;

  f32x4 acc[4][4] = {};
  int lr = lane >> 2, lc = lane & 3;
  int l15 = lane & 15, qd = lane >> 4;

  for (int k0 = 0; k0 < 512; k0 += 32) {
#pragma unroll
    for (int h = 0; h < 2; ++h) {
      int q = wave * 2 + h;
      int row = q * 16 + lr;
      async_copy16(xtile + (long)row * 512 + k0 + lc * 8, &a_sm[q * 512]);
      async_copy16(wtile + (long)row * 512 + k0 + lc * 8, &b_sm[q * 512]);
    }
    __syncthreads();
    bf16x8 af[4], bfr[4];
#pragma unroll
    for (int t = 0; t < 4; ++t) {
      af[t]  = *(const bf16x8*)&a_sm[(wr * 64 + t * 16 + l15) * 32 + qd * 8];
      bfr[t] = *(const bf16x8*)&b_sm[(wcol * 64 + t * 16 + l15) * 32 + qd * 8];
    }
#pragma unroll
    for (int i = 0; i < 4; ++i)
#pragma unroll
      for (int j = 0; j < 4; ++j)
        acc[i][j] = __builtin_amdgcn_mfma_f32_16x16x32_bf16(af[i], bfr[j], acc[i][j], 0, 0, 0);
    __syncthreads();
  }

  if (nt < 4) {
    // v path: bias, cast bf16, transpose in LDS, write vt coalesced-ish.
    // tr layout: [d(128)][b*16 + t_l] pitch 136.
    const float* bias = bv + nt * 128;
#pragma unroll
    for (int i = 0; i < 4; ++i)
#pragma unroll
      for (int j = 0; j < 4; ++j) {
        int col = wcol * 64 + j * 16 + l15;
        float bz = bias[col];
#pragma unroll
        for (int r = 0; r < 4; ++r) {
          int row = wr * 64 + i * 16 + qd * 4 + r;   // row = t_l*8 + b
          tr[col * 136 + (row & 7) * 16 + (row >> 3)] = (__bf16)(acc[i][j][r] + bz);
        }
      }
    __syncthreads();
    int cbase = (mt >> 3) * 8;        // chunk c * 8
    int s0 = (mt & 7) * 16;           // s offset within chunk
#pragma unroll
    for (int it = 0; it < 4; ++it) {
      int p = it * 256 + tid;         // 1024 (d,b) pairs
      int d = p & 127, b = p >> 7;
      bf16x8 u0 = *(const bf16x8*)&tr[d * 136 + b * 16];
      bf16x8 u1 = *(const bf16x8*)&tr[d * 136 + b * 16 + 8];
      __bf16* dst = vt + ((long)(cbase + b) * 512 + nt * 128 + d) * 128 + s0;
      *(bf16x8*)dst = u0;
      *(bf16x8*)(dst + 8) = u1;
    }
    return;
  }

  const float* bias; bool sig = false;
  __bf16* dstb = nullptr; float* dstf = nullptr;
  if (nt == 4)      { bias = bk; dstb = kout; }
  else if (nt == 5) { bias = bq; dstb = qout; }
  else              { bias = ba; dstf = aout; sig = true; }

#pragma unroll
  for (int i = 0; i < 4; ++i)
#pragma unroll
    for (int j = 0; j < 4; ++j) {
      int col = wcol * 64 + j * 16 + l15;
      float bz = bias[col];
#pragma unroll
      for (int r = 0; r < 4; ++r) {
        int row = wr * 64 + i * 16 + qd * 4 + r;
        float z = acc[i][j][r] + bz;
        long addr = ((long)mt * 128 + row) * 128 + col;
        if (sig) dstf[addr] = 1.f / (1.f + __expf(-z));
        else     dstb[addr] = (__bf16)z;
      }
    }
}

// ---- scan_cp: cumprod; emits qb/kbs bf16 natural, kt transposed, cpend ----
__global__ __launch_bounds__(256) void scan_cp(const float* __restrict__ a,
                                               const __bf16* __restrict__ k,
                                               const __bf16* __restrict__ q,
                                               __bf16* __restrict__ kbs,
                                               __bf16* __restrict__ qb,
                                               __bf16* __restrict__ kt,
                                               float* __restrict__ cpend) {
  int idx = blockIdx.x * 256 + threadIdx.x;  // 16384 = 16c*8b*128n
  int n = idx & 127;
  int b = (idx >> 7) & 7;
  int c = idx >> 10;
  long base = ((long)c * 1024 + b) * 128 + n;
  float cp = 1.f;
  __bf16 ktbuf[128];
#pragma unroll
  for (int tt = 0; tt < 128; ++tt) {
    long off = base + (long)tt * 1024;
    float av = fmaxf(a[off], EPSV);
    cp *= av;
    float kk = (float)k[off] / (cp + EPSV);
    float qq = (float)q[off] * cp;
    __bf16 kh = (__bf16)kk;
    kbs[off] = kh;
    qb[off] = (__bf16)qq;
    ktbuf[tt] = kh;
  }
  cpend[(c * 8 + b) * 128 + n] = cp;
  __bf16* dst = kt + ((long)((c * 8 + b) * 128 + n)) * 128;
#pragma unroll
  for (int i = 0; i < 16; ++i) {
    bf16x8 h;
#pragma unroll
    for (int j = 0; j < 8; ++j) h[j] = ktbuf[i * 8 + j];
    *(bf16x8*)(dst + i * 8) = h;
  }
}

// ---- gmm: Gt[d,n] = cpend[n] * sum_s vt[d,s]*kt[n,s].  grid 512 = cb*4+dt ----
__global__ __launch_bounds__(256) void gmm(const __bf16* __restrict__ vt,
                                           const __bf16* __restrict__ kt,
                                           const float* __restrict__ cpend,
                                           __bf16* __restrict__ Gt) {
  int tid = threadIdx.x, lane = tid & 63, wave = tid >> 6;
  int wr = wave >> 1, wc = wave & 1;
  int l15 = lane & 15, qd = lane >> 4;
  int cb = blockIdx.x >> 2, dt = blockIdx.x & 3;
  const __bf16* vbase = vt + ((long)cb * 512 + dt * 128) * 128;
  const __bf16* kbase = kt + (long)cb * 16384;
  f32x4 acc[4][4] = {};
#pragma unroll
  for (int kk = 0; kk < 4; ++kk) {
    int k0 = kk * 32;
    bf16x8 af[4], bfr[4];
#pragma unroll
    for (int i = 0; i < 4; ++i)
      af[i] = *(const bf16x8*)(vbase + (long)(wr * 64 + i * 16 + l15) * 128 + k0 + qd * 8);
#pragma unroll
    for (int j = 0; j < 4; ++j)
      bfr[j] = *(const bf16x8*)(kbase + (long)(wc * 64 + j * 16 + l15) * 128 + k0 + qd * 8);
#pragma unroll
    for (int i = 0; i < 4; ++i)
#pragma unroll
      for (int j = 0; j < 4; ++j)
        acc[i][j] = __builtin_amdgcn_mfma_f32_16x16x32_bf16(af[i], bfr[j], acc[i][j], 0, 0, 0);
  }
  float ce[4];
#pragma unroll
  for (int j = 0; j < 4; ++j) ce[j] = cpend[cb * 128 + wc * 64 + j * 16 + l15];
#pragma unroll
  for (int i = 0; i < 4; ++i)
#pragma unroll
    for (int j = 0; j < 4; ++j) {
      int col = wc * 64 + j * 16 + l15;
#pragma unroll
      for (int r = 0; r < 4; ++r) {
        int row = wr * 64 + i * 16 + qd * 4 + r;
        Gt[((long)cb * 512 + dt * 128 + row) * 128 + col] = (__bf16)(acc[i][j][r] * ce[j]);
      }
    }
}

// ---- scan_state: fp32 scan over chunks on Gt(bf16); emits St bf16 ----
__global__ __launch_bounds__(256) void scan_state(const __bf16* __restrict__ Gt,
                                                  const float* __restrict__ cpend,
                                                  __bf16* __restrict__ St) {
  long e = (long)blockIdx.x * 256 + threadIdx.x;  // 524288 = 8b*512d*128n
  int n = (int)(e & 127);
  int b = (int)(e >> 16);
  float S = 0.f;
#pragma unroll
  for (int c = 0; c < 16; ++c) {
    long idx = (long)c * 524288 + e;
    float g = (float)Gt[idx];
    St[idx] = (__bf16)S;
    S = g + S * cpend[(c * 8 + b) * 128 + n];
  }
}

// ---- ymm: y^T[d,t] = sum_s vt[d,s]*A[t,s] + sum_n St[d,n]*qb[t,n] ----
__global__ __launch_bounds__(256) void ymm(const __bf16* __restrict__ qb,
                                           const __bf16* __restrict__ kbs,
                                           const __bf16* __restrict__ vt,
                                           const __bf16* __restrict__ St,
                                           float* __restrict__ out) {
  __shared__ __bf16 A_lds[128 * 136];
  int tid = threadIdx.x, lane = tid & 63, wave = tid >> 6;
  int wr = wave >> 1, wc = wave & 1;
  int l15 = lane & 15, qd = lane >> 4;
  int cb = blockIdx.x >> 2, dt = blockIdx.x & 3;
  int c = cb >> 3, b = cb & 7;
  const __bf16* qbase = qb + ((long)c * 1024 + b) * 128;
  const __bf16* kbase = kbs + ((long)c * 1024 + b) * 128;

  {
    f32x4 accA[4][4] = {};
#pragma unroll
    for (int kk = 0; kk < 4; ++kk) {
      int k0 = kk * 32;
      bf16x8 af[4], bfr[4];
#pragma unroll
      for (int i = 0; i < 4; ++i)
        af[i] = *(const bf16x8*)(qbase + (long)(wr * 64 + i * 16 + l15) * 1024 + k0 + qd * 8);
#pragma unroll
      for (int j = 0; j < 4; ++j)
        bfr[j] = *(const bf16x8*)(kbase + (long)(wc * 64 + j * 16 + l15) * 1024 + k0 + qd * 8);
#pragma unroll
      for (int i = 0; i < 4; ++i)
#pragma unroll
        for (int j = 0; j < 4; ++j)
          accA[i][j] = __builtin_amdgcn_mfma_f32_16x16x32_bf16(af[i], bfr[j], accA[i][j], 0, 0, 0);
    }
#pragma unroll
    for (int i = 0; i < 4; ++i)
#pragma unroll
      for (int j = 0; j < 4; ++j) {
        int s = wc * 64 + j * 16 + l15;
#pragma unroll
        for (int r = 0; r < 4; ++r) {
          int t = wr * 64 + i * 16 + qd * 4 + r;
          A_lds[t * 136 + s] = (s <= t) ? (__bf16)accA[i][j][r] : (__bf16)0.f;
        }
      }
  }
  __syncthreads();

  f32x4 acc[4][4] = {};
  const __bf16* vbase = vt + ((long)cb * 512 + dt * 128) * 128;
  const __bf16* sbase = St + ((long)cb * 512 + dt * 128) * 128;
#pragma unroll
  for (int kk = 0; kk < 4; ++kk) {
    int k0 = kk * 32;
    bf16x8 af[4], bfr[4];
#pragma unroll
    for (int i = 0; i < 4; ++i)
      af[i] = *(const bf16x8*)(vbase + (long)(wr * 64 + i * 16 + l15) * 128 + k0 + qd * 8);
#pragma unroll
    for (int j = 0; j < 4; ++j)
      bfr[j] = *(const bf16x8*)&A_lds[(wc * 64 + j * 16 + l15) * 136 + k0 + qd * 8];
#pragma unroll
    for (int i = 0; i < 4; ++i)
#pragma unroll
      for (int j = 0; j < 4; ++j)
        acc[i][j] = __builtin_amdgcn_mfma_f32_16x16x32_bf16(af[i], bfr[j], acc[i][j], 0, 0, 0);
  }
#pragma unroll
  for (int kk = 0; kk < 4; ++kk) {
    int k0 = kk * 32;
    bf16x8 af[4], bfr[4];
#pragma unroll
    for (int i = 0; i < 4; ++i)
      af[i] = *(const bf16x8*)(sbase + (long)(wr * 64 + i * 16 + l15) * 128 + k0 + qd * 8);
#pragma unroll
    for (int j = 0; j < 4; ++j)
      bfr[j] = *(const bf16x8*)(qbase + (long)(wc * 64 + j * 16 + l15) * 1024 + k0 + qd * 8);
#pragma unroll
    for (int i = 0; i < 4; ++i)
#pragma unroll
      for (int j = 0; j < 4; ++j)
        acc[i][j] = __builtin_amdgcn_mfma_f32_16x16x32_bf16(af[i], bfr[j], acc[i][j], 0, 0, 0);
  }

#pragma unroll
  for (int i = 0; i < 4; ++i)
#pragma unroll
    for (int j = 0; j < 4; ++j) {
      int colt = wc * 64 + j * 16 + l15;
      long addr = ((long)(c * 128 + colt) * 8 + b) * 512 + dt * 128 + wr * 64 + i * 16 + qd * 4;
      *(float4*)(out + addr) = *(float4*)&acc[i][j];
    }
}

extern "C" void kernel_launch(void* const* d_in, const int* in_sizes, int n_in,
                              void* d_out, int out_size, void* d_ws, size_t ws_size,
                              hipStream_t stream) {
  const float* x  = (const float*)d_in[0];
  const float* Wv = (const float*)d_in[1];
  const float* bv = (const float*)d_in[2];
  const float* Wk = (const float*)d_in[3];
  const float* bk = (const float*)d_in[4];
  const float* Wq = (const float*)d_in[5];
  const float* bq = (const float*)d_in[6];
  const float* Wa = (const float*)d_in[7];
  const float* ba = (const float*)d_in[8];
  float* out = (float*)d_out;
  float* ws = (float*)d_ws;

  // float-unit offsets; total 20,168,704 fl = 80.7 MB
  float*  a_buf = ws;                          // 2,097,152 fl
  __bf16* qb    = (__bf16*)(ws + 2097152);     // 2,097,152 bf
  __bf16* kbs   = (__bf16*)(ws + 3145728);     // 2,097,152 bf
  __bf16* kt    = (__bf16*)(ws + 4194304);     // 2,097,152 bf
  __bf16* vt    = (__bf16*)(ws + 5242880);     // 8,388,608 bf
  __bf16* k_raw = (__bf16*)(ws + 9437184);     // 2,097,152 bf
  __bf16* q_raw = (__bf16*)(ws + 10485760);    // 2,097,152 bf
  __bf16* xb    = (__bf16*)(ws + 11534336);    // 8,388,608 bf
  __bf16* Wcat  = (__bf16*)(ws + 15728640);    // 458,752 bf
  __bf16* Gt    = xb;                          // overlay: xb dead after proj
  __bf16* St    = (__bf16*)(ws + 15958016);    // 8,388,608 bf
  float*  cpend = ws + 20152320;               // 16,384 fl

  conv_bf16<<<4096, 256, 0, stream>>>(x, xb);
  conv_w<<<224, 256, 0, stream>>>(Wv, Wk, Wq, Wa, Wcat);
  proj_mfma<<<dim3(128, 7), 256, 0, stream>>>(xb, Wcat, bv, bk, bq, ba,
                                              vt, k_raw, q_raw, a_buf);
  scan_cp<<<64, 256, 0, stream>>>(a_buf, k_raw, q_raw, kbs, qb, kt, cpend);
  gmm<<<512, 256, 0, stream>>>(vt, kt, cpend, Gt);
  scan_state<<<2048, 256, 0, stream>>>(Gt, cpend, St);
  ymm<<<512, 256, 0, stream>>>(qb, kbs, vt, St, out);
}